// Round 1
// baseline (1125.264 us; speedup 1.0000x reference)
//
#include <hip/hip_runtime.h>

// GNNML3: 3x (SpectConv + gated linear) + fc2, N=50k nodes, E=1.6M edges, K=10 supports.
// Strategy: XW[n,k,:] = x[n,:]@W[k]  (dense, tiny)
//           edge:  m = sum_k ea[e,k]*XW[src,k,:]; atomicAdd acc[dst,:]
//           epilogue: concat(relu(acc+b), (x@U+ub)*(x@V+vb)); layer3 fuses fc2.

constexpr int K  = 10;   // spectral supports
constexpr int C1 = 32;   // conv out
constexpr int C2 = 16;   // gate out
constexpr int CC = 48;   // concat width

// XW[n,k,c'] = sum_c x[n,c] * W[k,c,c']   (W: [K,CIN,32] row-major)
template<int CIN>
__global__ __launch_bounds__(256)
void xw_kernel(const float* __restrict__ x, const float* __restrict__ W,
               float* __restrict__ XW, int N) {
    __shared__ float Ws[K * CIN * C1];
    for (int i = threadIdx.x; i < K * CIN * C1; i += 256) Ws[i] = W[i];
    __syncthreads();
    int node = blockIdx.x * 8 + (int)(threadIdx.x >> 5);
    int cp   = threadIdx.x & 31;
    if (node >= N) return;
    float xv[CIN];
#pragma unroll
    for (int c = 0; c < CIN; ++c) xv[c] = x[(size_t)node * CIN + c];
#pragma unroll
    for (int k = 0; k < K; ++k) {
        float a = 0.f;
#pragma unroll
        for (int c = 0; c < CIN; ++c) a = fmaf(xv[c], Ws[(k * CIN + c) * C1 + cp], a);
        XW[(size_t)node * (K * C1) + k * C1 + cp] = a;
    }
}

// one edge per 32-lane half-wave; lane = output channel c'
__global__ __launch_bounds__(256)
void edge_kernel(const float* __restrict__ XW, const float* __restrict__ ea,
                 const int* __restrict__ src, const int* __restrict__ dst,
                 float* __restrict__ acc, int E) {
    int gid = blockIdx.x * 256 + threadIdx.x;
    int e   = gid >> 5;
    if (e >= E) return;
    int cp = threadIdx.x & 31;
    int s  = src[e];
    int d  = dst[e];
    const float* xw  = XW + (size_t)s * (K * C1) + cp;
    const float* eap = ea + (size_t)e * K;
    float m = 0.f;
#pragma unroll
    for (int k = 0; k < K; ++k) m = fmaf(eap[k], xw[k * C1], m);
    atomicAdd(acc + (size_t)d * C1 + cp, m);
}

// per node: xnext = [relu(acc+b) (32) | (x@U+ub)*(x@V+vb) (16)]
// FINAL: out[n] = xnext . fc2_w + fc2_b  (16-lane reduce)
template<int CIN, bool FINAL>
__global__ __launch_bounds__(256)
void epilogue_kernel(const float* __restrict__ acc, const float* __restrict__ b,
                     const float* __restrict__ x, const float* __restrict__ U,
                     const float* __restrict__ ub, const float* __restrict__ V,
                     const float* __restrict__ vb, float* __restrict__ xnext,
                     const float* __restrict__ fc2w, const float* __restrict__ fc2b,
                     float* __restrict__ out, int N) {
    int node = blockIdx.x * 16 + (int)(threadIdx.x >> 4);
    int cp   = threadIdx.x & 15;
    if (node >= N) return;
    float r0 = acc[(size_t)node * C1 + cp]      + b[cp];
    float r1 = acc[(size_t)node * C1 + 16 + cp] + b[16 + cp];
    r0 = r0 > 0.f ? r0 : 0.f;
    r1 = r1 > 0.f ? r1 : 0.f;
    float u = ub[cp], v = vb[cp];
#pragma unroll
    for (int c = 0; c < CIN; ++c) {
        float xc = x[(size_t)node * CIN + c];
        u = fmaf(xc, U[c * C2 + cp], u);
        v = fmaf(xc, V[c * C2 + cp], v);
    }
    float g = u * v;
    if (!FINAL) {
        xnext[(size_t)node * CC + cp]      = r0;
        xnext[(size_t)node * CC + 16 + cp] = r1;
        xnext[(size_t)node * CC + 32 + cp] = g;
    } else {
        float dp = r0 * fc2w[cp] + r1 * fc2w[16 + cp] + g * fc2w[32 + cp];
#pragma unroll
        for (int off = 8; off; off >>= 1) dp += __shfl_xor(dp, off, 16);
        if (cp == 0) out[node] = dp + fc2b[0];
    }
}

extern "C" void kernel_launch(void* const* d_in, const int* in_sizes, int n_in,
                              void* d_out, int out_size, void* d_ws, size_t ws_size,
                              hipStream_t stream) {
    const float* x   = (const float*)d_in[0];
    const float* ea  = (const float*)d_in[1];
    const int*   ei  = (const int*)d_in[2];
    const int N = in_sizes[0];        // NIN == 1
    const int E = in_sizes[1] / K;
    const int* srcp = ei;
    const int* dstp = ei + E;

    const float *W1 = (const float*)d_in[3],  *b1 = (const float*)d_in[4];
    const float *U1 = (const float*)d_in[5],  *ub1 = (const float*)d_in[6];
    const float *V1 = (const float*)d_in[7],  *vb1 = (const float*)d_in[8];
    const float *W2 = (const float*)d_in[9],  *b2 = (const float*)d_in[10];
    const float *U2 = (const float*)d_in[11], *ub2 = (const float*)d_in[12];
    const float *V2 = (const float*)d_in[13], *vb2 = (const float*)d_in[14];
    const float *W3 = (const float*)d_in[15], *b3 = (const float*)d_in[16];
    const float *U3 = (const float*)d_in[17], *ub3 = (const float*)d_in[18];
    const float *V3 = (const float*)d_in[19], *vb3 = (const float*)d_in[20];
    const float *fc2w = (const float*)d_in[21], *fc2b = (const float*)d_in[22];

    float* XW  = (float*)d_ws;                    // N*K*C1  = 16.0M floats (64 MB)
    float* acc = XW  + (size_t)N * K * C1;        // N*C1    =  1.6M floats (6.4 MB)
    float* x2  = acc + (size_t)N * C1;            // N*CC    =  2.4M floats (9.6 MB)
    float* x3  = x2  + (size_t)N * CC;            // N*CC    =  2.4M floats (9.6 MB)

    const int xwBlocks = (N + 7) / 8;
    const int edBlocks = (int)(((size_t)E * 32 + 255) / 256);
    const int epBlocks = (N + 15) / 16;
    const size_t accBytes = (size_t)N * C1 * sizeof(float);

    // ---- layer 1 (CIN = 1) ----
    hipMemsetAsync(acc, 0, accBytes, stream);
    xw_kernel<1><<<xwBlocks, 256, 0, stream>>>(x, W1, XW, N);
    edge_kernel<<<edBlocks, 256, 0, stream>>>(XW, ea, srcp, dstp, acc, E);
    epilogue_kernel<1, false><<<epBlocks, 256, 0, stream>>>(
        acc, b1, x, U1, ub1, V1, vb1, x2, nullptr, nullptr, nullptr, N);

    // ---- layer 2 (CIN = 48) ----
    hipMemsetAsync(acc, 0, accBytes, stream);
    xw_kernel<CC><<<xwBlocks, 256, 0, stream>>>(x2, W2, XW, N);
    edge_kernel<<<edBlocks, 256, 0, stream>>>(XW, ea, srcp, dstp, acc, E);
    epilogue_kernel<CC, false><<<epBlocks, 256, 0, stream>>>(
        acc, b2, x2, U2, ub2, V2, vb2, x3, nullptr, nullptr, nullptr, N);

    // ---- layer 3 (CIN = 48, fused fc2) ----
    hipMemsetAsync(acc, 0, accBytes, stream);
    xw_kernel<CC><<<xwBlocks, 256, 0, stream>>>(x3, W3, XW, N);
    edge_kernel<<<edBlocks, 256, 0, stream>>>(XW, ea, srcp, dstp, acc, E);
    epilogue_kernel<CC, true><<<epBlocks, 256, 0, stream>>>(
        acc, b3, x3, U3, ub3, V3, vb3, nullptr, fc2w, fc2b, (float*)d_out, N);
}

// Round 2
// 1012.374 us; speedup vs baseline: 1.1115x; 1.1115x over previous
//
#include <hip/hip_runtime.h>

// GNNML3: 3x (SpectConv + gated linear) + fc2, N=50k nodes, E=1.6M edges, K=10 supports.
// R2: sort edges by src (device counting sort) so XW gathers become sequential;
//     layer-1 (CIN=1) folds W1 into the edge kernel (no XW table at all).

constexpr int K  = 10;   // spectral supports
constexpr int C1 = 32;   // conv out
constexpr int C2 = 16;   // gate out
constexpr int CC = 48;   // concat width

// ---------------- counting sort by src ----------------
__global__ __launch_bounds__(256)
void hist_kernel(const int* __restrict__ src, int* __restrict__ hist, int E) {
    int i = blockIdx.x * 256 + threadIdx.x;
    if (i < E) atomicAdd(&hist[src[i]], 1);
}

// single-block exclusive scan over n (<= 1024*chunk) histogram entries
__global__ __launch_bounds__(1024)
void scan_kernel(const int* __restrict__ hist, int* __restrict__ offs, int n) {
    __shared__ int sums[1024];
    int t = threadIdx.x;
    int chunk = (n + 1023) >> 10;
    int lo = t * chunk, hi = min(lo + chunk, n);
    int s = 0;
    for (int i = lo; i < hi; ++i) s += hist[i];
    sums[t] = s;
    __syncthreads();
    for (int off = 1; off < 1024; off <<= 1) {
        int addv = (t >= off) ? sums[t - off] : 0;
        __syncthreads();
        sums[t] += addv;
        __syncthreads();
    }
    int run = sums[t] - s;  // exclusive base of this thread's chunk
    for (int i = lo; i < hi; ++i) { offs[i] = run; run += hist[i]; }
}

__global__ __launch_bounds__(256)
void scatter_kernel(const float* __restrict__ ea, const int* __restrict__ src,
                    const int* __restrict__ dst, int* __restrict__ offs,
                    float* __restrict__ ea_s, int* __restrict__ src_s,
                    int* __restrict__ dst_s, int E) {
    int e = blockIdx.x * 256 + threadIdx.x;
    if (e >= E) return;
    int s = src[e];
    int pos = atomicAdd(&offs[s], 1);   // rank within bucket (order nondet., sum assoc-tolerant)
    src_s[pos] = s;
    dst_s[pos] = dst[e];
    const float* ep = ea + (size_t)e * K;
    float* eo = ea_s + (size_t)pos * K;
#pragma unroll
    for (int k = 0; k < K; ++k) eo[k] = ep[k];
}

// ---------------- dense XW = x @ W[k] ----------------
// XW[n,k,c'] = sum_c x[n,c] * W[k,c,c']   (W: [K,CIN,32] row-major)
template<int CIN>
__global__ __launch_bounds__(256)
void xw_kernel(const float* __restrict__ x, const float* __restrict__ W,
               float* __restrict__ XW, int N) {
    __shared__ float Ws[K * CIN * C1];
    for (int i = threadIdx.x; i < K * CIN * C1; i += 256) Ws[i] = W[i];
    __syncthreads();
    int node = blockIdx.x * 8 + (int)(threadIdx.x >> 5);
    int cp   = threadIdx.x & 31;
    if (node >= N) return;
    float xv[CIN];
#pragma unroll
    for (int c = 0; c < CIN; ++c) xv[c] = x[(size_t)node * CIN + c];
#pragma unroll
    for (int k = 0; k < K; ++k) {
        float a = 0.f;
#pragma unroll
        for (int c = 0; c < CIN; ++c) a = fmaf(xv[c], Ws[(k * CIN + c) * C1 + cp], a);
        XW[(size_t)node * (K * C1) + k * C1 + cp] = a;
    }
}

// ---------------- edge kernels ----------------
// layer 1 (CIN=1): m[c'] = x[s] * sum_k ea[k]*W1[k,c'] ; W1 (10x32) in LDS
__global__ __launch_bounds__(256)
void edge1_kernel(const float* __restrict__ x, const float* __restrict__ W1,
                  const float* __restrict__ ea, const int* __restrict__ src,
                  const int* __restrict__ dst, float* __restrict__ acc, int E) {
    __shared__ float Ws[K * C1];
    for (int i = threadIdx.x; i < K * C1; i += 256) Ws[i] = W1[i];
    __syncthreads();
    int gid = blockIdx.x * 256 + threadIdx.x;
    int e   = gid >> 5;
    if (e >= E) return;
    int cp = threadIdx.x & 31;
    int s  = src[e];
    int d  = dst[e];
    float xv = x[s];                       // broadcast (same addr across 32 lanes)
    const float* eap = ea + (size_t)e * K;
    float m = 0.f;
#pragma unroll
    for (int k = 0; k < K; ++k) m = fmaf(eap[k], Ws[k * C1 + cp], m);
    atomicAdd(acc + (size_t)d * C1 + cp, m * xv);
}

// layers 2/3: one edge per 32-lane group; lane = output channel c'
__global__ __launch_bounds__(256)
void edge_kernel(const float* __restrict__ XW, const float* __restrict__ ea,
                 const int* __restrict__ src, const int* __restrict__ dst,
                 float* __restrict__ acc, int E) {
    int gid = blockIdx.x * 256 + threadIdx.x;
    int e   = gid >> 5;
    if (e >= E) return;
    int cp = threadIdx.x & 31;
    int s  = src[e];
    int d  = dst[e];
    const float* xw  = XW + (size_t)s * (K * C1) + cp;
    const float* eap = ea + (size_t)e * K;
    float m = 0.f;
#pragma unroll
    for (int k = 0; k < K; ++k) m = fmaf(eap[k], xw[k * C1], m);
    atomicAdd(acc + (size_t)d * C1 + cp, m);
}

// ---------------- node epilogue ----------------
// xnext = [relu(acc+b) (32) | (x@U+ub)*(x@V+vb) (16)] ; FINAL fuses fc2 dot
template<int CIN, bool FINAL>
__global__ __launch_bounds__(256)
void epilogue_kernel(const float* __restrict__ acc, const float* __restrict__ b,
                     const float* __restrict__ x, const float* __restrict__ U,
                     const float* __restrict__ ub, const float* __restrict__ V,
                     const float* __restrict__ vb, float* __restrict__ xnext,
                     const float* __restrict__ fc2w, const float* __restrict__ fc2b,
                     float* __restrict__ out, int N) {
    int node = blockIdx.x * 16 + (int)(threadIdx.x >> 4);
    int cp   = threadIdx.x & 15;
    if (node >= N) return;
    float r0 = acc[(size_t)node * C1 + cp]      + b[cp];
    float r1 = acc[(size_t)node * C1 + 16 + cp] + b[16 + cp];
    r0 = r0 > 0.f ? r0 : 0.f;
    r1 = r1 > 0.f ? r1 : 0.f;
    float u = ub[cp], v = vb[cp];
#pragma unroll
    for (int c = 0; c < CIN; ++c) {
        float xc = x[(size_t)node * CIN + c];
        u = fmaf(xc, U[c * C2 + cp], u);
        v = fmaf(xc, V[c * C2 + cp], v);
    }
    float g = u * v;
    if (!FINAL) {
        xnext[(size_t)node * CC + cp]      = r0;
        xnext[(size_t)node * CC + 16 + cp] = r1;
        xnext[(size_t)node * CC + 32 + cp] = g;
    } else {
        float dp = r0 * fc2w[cp] + r1 * fc2w[16 + cp] + g * fc2w[32 + cp];
#pragma unroll
        for (int off = 8; off; off >>= 1) dp += __shfl_xor(dp, off, 16);
        if (cp == 0) out[node] = dp + fc2b[0];
    }
}

extern "C" void kernel_launch(void* const* d_in, const int* in_sizes, int n_in,
                              void* d_out, int out_size, void* d_ws, size_t ws_size,
                              hipStream_t stream) {
    const float* x   = (const float*)d_in[0];
    const float* ea  = (const float*)d_in[1];
    const int*   ei  = (const int*)d_in[2];
    const int N = in_sizes[0];        // NIN == 1
    const int E = in_sizes[1] / K;
    const int* srcp = ei;
    const int* dstp = ei + E;

    const float *W1 = (const float*)d_in[3],  *b1 = (const float*)d_in[4];
    const float *U1 = (const float*)d_in[5],  *ub1 = (const float*)d_in[6];
    const float *V1 = (const float*)d_in[7],  *vb1 = (const float*)d_in[8];
    const float *W2 = (const float*)d_in[9],  *b2 = (const float*)d_in[10];
    const float *U2 = (const float*)d_in[11], *ub2 = (const float*)d_in[12];
    const float *V2 = (const float*)d_in[13], *vb2 = (const float*)d_in[14];
    const float *W3 = (const float*)d_in[15], *b3 = (const float*)d_in[16];
    const float *U3 = (const float*)d_in[17], *ub3 = (const float*)d_in[18];
    const float *V3 = (const float*)d_in[19], *vb3 = (const float*)d_in[20];
    const float *fc2w = (const float*)d_in[21], *fc2b = (const float*)d_in[22];

    // ---- workspace layout ----
    float* XW  = (float*)d_ws;                    // N*K*C1 floats (64 MB)
    float* acc = XW  + (size_t)N * K * C1;        // N*C1 (6.4 MB)
    float* x2  = acc + (size_t)N * C1;            // N*CC (9.6 MB)
    float* x3  = x2  + (size_t)N * CC;            // N*CC (9.6 MB)
    float* ea_s  = x3 + (size_t)N * CC;           // E*K (64 MB)
    int*   src_s = (int*)(ea_s + (size_t)E * K);  // E (6.4 MB)
    int*   dst_s = src_s + E;                     // E (6.4 MB)
    int*   hist  = dst_s + E;                     // N
    int*   offs  = hist + N;                      // N
    size_t needSorted = (size_t)(offs + N - (int*)d_ws) * sizeof(int);
    bool useSorted = ws_size >= needSorted;

    const int xwBlocks = (N + 7) / 8;
    const int edBlocks = (int)(((size_t)E * 32 + 255) / 256);
    const int eBlocks  = (E + 255) / 256;
    const int epBlocks = (N + 15) / 16;
    const size_t accBytes = (size_t)N * C1 * sizeof(float);

    const float* eaL = ea;  const int* srcL = srcp;  const int* dstL = dstp;
    if (useSorted) {
        hipMemsetAsync(hist, 0, (size_t)N * sizeof(int), stream);
        hist_kernel<<<eBlocks, 256, 0, stream>>>(srcp, hist, E);
        scan_kernel<<<1, 1024, 0, stream>>>(hist, offs, N);
        scatter_kernel<<<eBlocks, 256, 0, stream>>>(ea, srcp, dstp, offs,
                                                    ea_s, src_s, dst_s, E);
        eaL = ea_s; srcL = src_s; dstL = dst_s;
    }

    // ---- layer 1 (CIN = 1, fused W1, no XW) ----
    hipMemsetAsync(acc, 0, accBytes, stream);
    edge1_kernel<<<edBlocks, 256, 0, stream>>>(x, W1, ea, srcp, dstp, acc, E);
    epilogue_kernel<1, false><<<epBlocks, 256, 0, stream>>>(
        acc, b1, x, U1, ub1, V1, vb1, x2, nullptr, nullptr, nullptr, N);

    // ---- layer 2 (CIN = 48) ----
    hipMemsetAsync(acc, 0, accBytes, stream);
    xw_kernel<CC><<<xwBlocks, 256, 0, stream>>>(x2, W2, XW, N);
    edge_kernel<<<edBlocks, 256, 0, stream>>>(XW, eaL, srcL, dstL, acc, E);
    epilogue_kernel<CC, false><<<epBlocks, 256, 0, stream>>>(
        acc, b2, x2, U2, ub2, V2, vb2, x3, nullptr, nullptr, nullptr, N);

    // ---- layer 3 (CIN = 48, fused fc2) ----
    hipMemsetAsync(acc, 0, accBytes, stream);
    xw_kernel<CC><<<xwBlocks, 256, 0, stream>>>(x3, W3, XW, N);
    edge_kernel<<<edBlocks, 256, 0, stream>>>(XW, eaL, srcL, dstL, acc, E);
    epilogue_kernel<CC, true><<<epBlocks, 256, 0, stream>>>(
        acc, b3, x3, U3, ub3, V3, vb3, nullptr, fc2w, fc2b, (float*)d_out, N);
}